// Round 9
// baseline (183.444 us; speedup 1.0000x reference)
//
#include <hip/hip_runtime.h>

typedef short short8 __attribute__((ext_vector_type(8)));
typedef float f32x4  __attribute__((ext_vector_type(4)));

constexpr int M_TOT  = 8 * 4096;   // 32768 pixels
constexpr int K_PROT = 1024;
constexpr int D_DIM  = 128;

// ws layout: xsq @0 (128 KB), psq @128K (4 KB), pfrag @132K (256 KB)
constexpr size_t WS_PSQ_OFF = (size_t)M_TOT * 4;
constexpr size_t WS_PF_OFF  = WS_PSQ_OFF + (size_t)K_PROT * 4;

constexpr int NORM_BLOCKS  = (M_TOT + K_PROT) / 8;  // 4224
constexpr int PFRAG_BLOCKS = 16384 / 256;           // 64 (single-part frags)

__device__ inline unsigned short bf16_rne(float f) {
  unsigned u = __builtin_bit_cast(unsigned, f);
  unsigned r = u + 0x7FFFu + ((u >> 16) & 1u);   // RNE
  return (unsigned short)(r >> 16);
}

// LDS-only barrier: ds ops complete (lgkmcnt), but do NOT drain in-flight
// global stores (vmcnt) like __syncthreads() would.
__device__ inline void barrier_lds() {
  asm volatile("s_waitcnt lgkmcnt(0)\n\ts_barrier" ::: "memory");
}

// ---------------------------------------------------------------------------
// Fused prep: row norms (xsq, psq) + proto fragment pre-swizzle (pf).
// Blocks [0, 4224): norms; blocks [4224, 4288): pfrag.
// pf (single bf16): g in [0,16384): ng=g>>8 (16-proto group), ks=(g>>6)&3,
// lane=g&63. proto = ng*16 + (lane&15), k = ks*32 + (lane>>4)*8 + j.
__global__ __launch_bounds__(256) void prep_kernel(
    const float* __restrict__ x, const float* __restrict__ p,
    float* __restrict__ xsq, float* __restrict__ psq, short* __restrict__ pf) {
  const int bx  = blockIdx.x;
  const int tid = threadIdx.x;
  if (bx < NORM_BLOCKS) {
    int group = bx * 8 + (tid >> 5);
    int lane  = tid & 31;
    if (group >= M_TOT + K_PROT) return;
    const float* row = (group < M_TOT) ? (x + (size_t)group * D_DIM)
                                       : (p + (size_t)(group - M_TOT) * D_DIM);
    float4 v = reinterpret_cast<const float4*>(row)[lane];
    float s = v.x * v.x + v.y * v.y + v.z * v.z + v.w * v.w;
    #pragma unroll
    for (int off = 16; off > 0; off >>= 1) s += __shfl_down(s, off, 32);
    if (lane == 0) {
      if (group < M_TOT) xsq[group] = s;
      else psq[group - M_TOT] = s;
    }
  } else {
    int g    = (bx - NORM_BLOCKS) * 256 + tid;   // 0..16383
    int lane = g & 63;
    int ks   = (g >> 6) & 3;
    int ng   = g >> 8;
    int proto = ng * 16 + (lane & 15);
    int k0    = ks * 32 + (lane >> 4) * 8;
    const float4* pr = (const float4*)(p + (size_t)proto * D_DIM + k0);
    float4 a = pr[0], b = pr[1];
    float e[8] = {a.x, a.y, a.z, a.w, b.x, b.y, b.z, b.w};
    short8 frag;
    #pragma unroll
    for (int j = 0; j < 8; ++j) frag[j] = (short)bf16_rne(e[j]);
    *(short8*)(pf + (size_t)g * 8) = frag;
  }
}

// ---------------------------------------------------------------------------
// Main: A=protos (pf via L2, lockstep -> L2-resident), B=pixels (LDS).
// R9: block = 32 pixels (grid 1024). The whole chunk's score tile
// (32 rows x 256 cols = 32 KB) fits ONE staging buffer ->
//   - one stage+drain round per chunk (8 barrier pairs total, was 16),
//   - ALL 4 waves stage simultaneously (wave-private col regions, no idle),
//   - drain = 1 KB fully-contiguous run per score row (fill-like pattern).
// C/D: col(lane&15)=pixel, row=(lane>>4)*4+reg = 4 consecutive protos.
__global__ __launch_bounds__(256, 2) void proto_mfma(
    const float* __restrict__ x, const float* __restrict__ p,
    const short* __restrict__ pf, const float* __restrict__ xsq,
    const float* __restrict__ psq,
    float* __restrict__ matched, float* __restrict__ scores) {
  __shared__ short xlds[8 * 64 * 8];    // 8 KB: [nt*4 + ks][lane][8], nt<2
  __shared__ float sbuf[32][260];       // 33.3 KB: [pixel][256 cols + 4 pad]
  __shared__ float sv[4][32];
  __shared__ int   si[4][32];
  __shared__ int   fidx[32];

  const int tid  = threadIdx.x;
  const int w    = tid >> 6;
  const int l    = tid & 63;
  const int m0   = blockIdx.x * 32;
  const int csub = (l >> 4) << 2;       // 0,4,8,12

  // ---- stage x tile (32 pix x 128 d) into LDS, B-frag order, bf16 ----
  #pragma unroll
  for (int i = 0; i < 2; ++i) {
    int piece = i * 256 + tid;          // 0..511
    int s = piece >> 6;                 // 0..7
    int ks = s & 3, nt = s >> 2;
    int pix = m0 + nt * 16 + (l & 15);
    int k0  = ks * 32 + (l >> 4) * 8;
    const float4* xr = (const float4*)(x + (size_t)pix * D_DIM + k0);
    float4 a = xr[0], b = xr[1];
    float e[8] = {a.x, a.y, a.z, a.w, b.x, b.y, b.z, b.w};
    short8 frag;
    #pragma unroll
    for (int j = 0; j < 8; ++j) frag[j] = (short)bf16_rne(e[j]);
    *(short8*)(xlds + (size_t)piece * 8) = frag;
  }
  __syncthreads();

  float xs[2];
  #pragma unroll
  for (int nt = 0; nt < 2; ++nt) xs[nt] = xsq[m0 + nt * 16 + (l & 15)];

  float best[2]; int bidx[2];
  #pragma unroll
  for (int nt = 0; nt < 2; ++nt) { best[nt] = -3.4e38f; bidx[nt] = 0; }

  for (int chunk = 0; chunk < 4; ++chunk) {
    f32x4 acc[4][2];
    #pragma unroll
    for (int mt = 0; mt < 4; ++mt)
      #pragma unroll
      for (int nt = 0; nt < 2; ++nt) acc[mt][nt] = (f32x4){0.f, 0.f, 0.f, 0.f};

    const int pgbase = chunk * 16 + w * 4;

    #pragma unroll
    for (int ks = 0; ks < 4; ++ks) {
      short8 pah[4], bh[2];
      #pragma unroll
      for (int mt = 0; mt < 4; ++mt)
        pah[mt] = *(const short8*)(pf + ((size_t)((pgbase + mt) * 4 + ks) * 64 + l) * 8);
      #pragma unroll
      for (int nt = 0; nt < 2; ++nt)
        bh[nt] = *(const short8*)(xlds + (size_t)(((nt * 4 + ks) * 64) + l) * 8);
      #pragma unroll
      for (int mt = 0; mt < 4; ++mt)
        #pragma unroll
        for (int nt = 0; nt < 2; ++nt)
          acc[mt][nt] = __builtin_amdgcn_mfma_f32_16x16x32_bf16(pah[mt], bh[nt], acc[mt][nt], 0, 0, 0);
    }

    // ---- epilogue: finalize scores + running per-pixel argmax ----
    #pragma unroll
    for (int mt = 0; mt < 4; ++mt) {
      int pbase = chunk * 256 + w * 64 + mt * 16 + csub;
      float psa[4];
      *(float4*)psa = *(const float4*)(psq + pbase);
      #pragma unroll
      for (int nt = 0; nt < 2; ++nt) {
        f32x4 o;
        {
          #pragma clang fp contract(off)
          #pragma unroll
          for (int r = 0; r < 4; ++r) {
            float t = (xs[nt] + psa[r]) - 2.0f * acc[mt][nt][r];
            o[r] = -t;
            if (o[r] > best[nt]) { best[nt] = o[nt == 0 ? r : r]; best[nt] = o[r]; bidx[nt] = pbase + r; }
          }
        }
        acc[mt][nt] = o;
      }
    }

    // ---- single stage+drain round: all waves stage their own col region ----
    #pragma unroll
    for (int mt = 0; mt < 4; ++mt)
      #pragma unroll
      for (int nt = 0; nt < 2; ++nt)
        *(f32x4*)&sbuf[nt * 16 + (l & 15)][w * 64 + mt * 16 + csub] = acc[mt][nt];
    barrier_lds();
    #pragma unroll
    for (int ps = 0; ps < 8; ++ps) {
      int idx = ps * 256 + tid;        // 0..2047
      int row = idx >> 6;              // 0..31 (4 rows per pass)
      int c4  = idx & 63;              // 0..63 (256 cols / 4)
      f32x4 v = *(const f32x4*)&sbuf[row][c4 * 4];
      *((f32x4*)(scores + (size_t)(m0 + row) * K_PROT + chunk * 256) + c4) = v;
    }
    barrier_lds();   // drain done before next chunk's stage overwrites sbuf
  }

  // ---- argmax reduce: butterfly over quads, then LDS over waves ----
  #pragma unroll
  for (int nt = 0; nt < 2; ++nt) {
    #pragma unroll
    for (int m = 16; m <= 32; m <<= 1) {
      float ov = __shfl_xor(best[nt], m);
      int   oi = __shfl_xor(bidx[nt], m);
      if (ov > best[nt] || (ov == best[nt] && oi < bidx[nt])) {
        best[nt] = ov; bidx[nt] = oi;
      }
    }
  }
  if (l < 16) {
    #pragma unroll
    for (int nt = 0; nt < 2; ++nt) {
      sv[w][nt * 16 + l] = best[nt];
      si[w][nt * 16 + l] = bidx[nt];
    }
  }
  __syncthreads();
  if (tid < 32) {
    float v = sv[0][tid]; int bi = si[0][tid];
    #pragma unroll
    for (int e = 1; e < 4; ++e) {
      float vv = sv[e][tid]; int ii = si[e][tid];
      if (vv > v || (vv == v && ii < bi)) { v = vv; bi = ii; }
    }
    fidx[tid] = bi;
  }
  __syncthreads();

  // ---- gather matched = original fp32 prototypes[argmax] ----
  #pragma unroll
  for (int q0 = 0; q0 < 4; ++q0) {
    int q = q0 * 256 + tid;            // 0..1023
    int pix = q >> 5, f4 = q & 31;
    float4 v = ((const float4*)(p + (size_t)fidx[pix] * D_DIM))[f4];
    *((f32x4*)(matched + (size_t)(m0 + pix) * D_DIM) + f4) = *(f32x4*)&v;
  }
}

// ---------------------------------------------------------------------------
extern "C" void kernel_launch(void* const* d_in, const int* in_sizes, int n_in,
                              void* d_out, int out_size, void* d_ws, size_t ws_size,
                              hipStream_t stream) {
  const float* x = (const float*)d_in[0];   // [B,N,D] fp32
  const float* p = (const float*)d_in[1];   // [K,D]   fp32

  float* matched = (float*)d_out;                            // [B,N,D]
  float* scores  = (float*)d_out + (size_t)M_TOT * D_DIM;    // [B,N,K]

  float* xsq = (float*)d_ws;
  float* psq = (float*)((char*)d_ws + WS_PSQ_OFF);
  short* pf  = (short*)((char*)d_ws + WS_PF_OFF);

  prep_kernel<<<NORM_BLOCKS + PFRAG_BLOCKS, 256, 0, stream>>>(x, p, xsq, psq, pf);
  proto_mfma<<<M_TOT / 32, 256, 0, stream>>>(x, p, pf, xsq, psq, matched, scores);
}

// Round 10
// 167.412 us; speedup vs baseline: 1.0958x; 1.0958x over previous
//
#include <hip/hip_runtime.h>

typedef short short8 __attribute__((ext_vector_type(8)));
typedef float f32x4  __attribute__((ext_vector_type(4)));

constexpr int M_TOT  = 8 * 4096;   // 32768 pixels
constexpr int K_PROT = 1024;
constexpr int D_DIM  = 128;

// ws layout: psq @0 (4 KB), pfrag @4K (256 KB)
constexpr size_t WS_PF_OFF = (size_t)K_PROT * 4;

constexpr int PSQ_BLOCKS   = K_PROT / 8;    // 128
constexpr int PFRAG_BLOCKS = 16384 / 256;   // 64

__device__ inline unsigned short bf16_rne(float f) {
  unsigned u = __builtin_bit_cast(unsigned, f);
  unsigned r = u + 0x7FFFu + ((u >> 16) & 1u);   // RNE
  return (unsigned short)(r >> 16);
}

// LDS-only barrier: ds ops complete (lgkmcnt), but do NOT drain in-flight
// global stores (vmcnt) like __syncthreads() would.
__device__ inline void barrier_lds() {
  asm volatile("s_waitcnt lgkmcnt(0)\n\ts_barrier" ::: "memory");
}

// ---------------------------------------------------------------------------
// Prep (small now: xsq moved in-block): psq blocks [0,128); pfrag [128,192).
// pf (single bf16): g in [0,16384): ng=g>>8 (16-proto group), ks=(g>>6)&3,
// lane=g&63. proto = ng*16 + (lane&15), k = ks*32 + (lane>>4)*8 + j.
__global__ __launch_bounds__(256) void prep_kernel(
    const float* __restrict__ p, float* __restrict__ psq,
    short* __restrict__ pf) {
  const int bx  = blockIdx.x;
  const int tid = threadIdx.x;
  if (bx < PSQ_BLOCKS) {
    int group = bx * 8 + (tid >> 5);
    int lane  = tid & 31;
    if (group >= K_PROT) return;
    float4 v = reinterpret_cast<const float4*>(p + (size_t)group * D_DIM)[lane];
    float s = v.x * v.x + v.y * v.y + v.z * v.z + v.w * v.w;
    #pragma unroll
    for (int off = 16; off > 0; off >>= 1) s += __shfl_down(s, off, 32);
    if (lane == 0) psq[group] = s;
  } else {
    int g    = (bx - PSQ_BLOCKS) * 256 + tid;   // 0..16383
    int lane = g & 63;
    int ks   = (g >> 6) & 3;
    int ng   = g >> 8;
    int proto = ng * 16 + (lane & 15);
    int k0    = ks * 32 + (lane >> 4) * 8;
    const float4* pr = (const float4*)(p + (size_t)proto * D_DIM + k0);
    float4 a = pr[0], b = pr[1];
    float e[8] = {a.x, a.y, a.z, a.w, b.x, b.y, b.z, b.w};
    short8 frag;
    #pragma unroll
    for (int j = 0; j < 8; ++j) frag[j] = (short)bf16_rne(e[j]);
    *(short8*)(pf + (size_t)g * 8) = frag;
  }
}

// ---------------------------------------------------------------------------
// Main: A=protos (pf via L2, lockstep -> L2-resident), B=pixels (LDS).
// R10 = R8 structure (64 pix/block, grid 512, 2 blocks/CU, lockstep staged
// drains with 512B runs, plain stores) but with EIGHT waves per block
// (512 threads): same pf streams per CU, same drain shape — only change is
// 4 waves/SIMD instead of 2 for latency interleave (the untested TLP lever;
// R3/R7's blocks/CU route multiplied pf streams and failed twice).
// Wave w (0..7) owns protos [chunk*256 + w*32, +32) = 2 mt tiles; acc[2][4].
// xsq computed in-block during x-staging (R3's proven trick; argmax invariant
// since xs shifts all of a pixel's scores equally). Prep shrinks to psq+pf.
__global__ __launch_bounds__(512, 4) void proto_mfma(
    const float* __restrict__ x, const float* __restrict__ p,
    const short* __restrict__ pf, const float* __restrict__ psq,
    float* __restrict__ matched, float* __restrict__ scores) {
  __shared__ short xlds[16 * 64 * 8];   // 16 KB: [nt*4 + ks][lane][8]
  __shared__ float sbuf[64][132];       // 33.8 KB staging (pad 4 -> 2-way banks)
  __shared__ float sv[8][64];
  __shared__ int   si[8][64];
  __shared__ int   fidx[64];
  __shared__ float xsqv[64];

  const int tid  = threadIdx.x;
  const int w    = tid >> 6;            // 0..7
  const int l    = tid & 63;
  const int m0   = blockIdx.x * 64;
  const int csub = (l >> 4) << 2;       // 0,4,8,12

  // xpart alias: [pixel 0..63][16 partials] = 4 KB inside sbuf (unused yet)
  float (*xpart)[16] = (float(*)[16])&sbuf[0][0];

  // ---- stage x tile into LDS in B-fragment order + xsq partials (once) ----
  #pragma unroll
  for (int i = 0; i < 2; ++i) {
    int piece = i * 512 + tid;          // 0..1023
    int s = piece >> 6;                 // 0..15
    int ks = s & 3, nt = s >> 2;
    int pix = m0 + nt * 16 + (l & 15);
    int k0  = ks * 32 + (l >> 4) * 8;
    const float4* xr = (const float4*)(x + (size_t)pix * D_DIM + k0);
    float4 a = xr[0], b = xr[1];
    float e[8] = {a.x, a.y, a.z, a.w, b.x, b.y, b.z, b.w};
    float ss = e[0]*e[0] + e[1]*e[1] + e[2]*e[2] + e[3]*e[3]
             + e[4]*e[4] + e[5]*e[5] + e[6]*e[6] + e[7]*e[7];
    xpart[nt * 16 + (l & 15)][ks * 4 + (l >> 4)] = ss;
    short8 frag;
    #pragma unroll
    for (int j = 0; j < 8; ++j) frag[j] = (short)bf16_rne(e[j]);
    *(short8*)(xlds + (size_t)piece * 8) = frag;
  }
  __syncthreads();

  if (tid < 64) {
    float s = 0.f;
    #pragma unroll
    for (int j = 0; j < 16; ++j) s += xpart[tid][j];
    xsqv[tid] = s;
  }
  __syncthreads();   // xsqv ready; sbuf free for score staging after this

  float xs[4];
  #pragma unroll
  for (int nt = 0; nt < 4; ++nt) xs[nt] = xsqv[nt * 16 + (l & 15)];

  float best[4]; int bidx[4];
  #pragma unroll
  for (int nt = 0; nt < 4; ++nt) { best[nt] = -3.4e38f; bidx[nt] = 0; }

  for (int chunk = 0; chunk < 4; ++chunk) {
    f32x4 acc[2][4];
    #pragma unroll
    for (int mt = 0; mt < 2; ++mt)
      #pragma unroll
      for (int nt = 0; nt < 4; ++nt) acc[mt][nt] = (f32x4){0.f, 0.f, 0.f, 0.f};

    const int pgbase = chunk * 16 + w * 2;

    #pragma unroll
    for (int ks = 0; ks < 4; ++ks) {
      short8 pah[2], bh[4];
      #pragma unroll
      for (int mt = 0; mt < 2; ++mt)
        pah[mt] = *(const short8*)(pf + ((size_t)((pgbase + mt) * 4 + ks) * 64 + l) * 8);
      #pragma unroll
      for (int nt = 0; nt < 4; ++nt)
        bh[nt] = *(const short8*)(xlds + (size_t)(((nt * 4 + ks) * 64) + l) * 8);
      #pragma unroll
      for (int mt = 0; mt < 2; ++mt)
        #pragma unroll
        for (int nt = 0; nt < 4; ++nt)
          acc[mt][nt] = __builtin_amdgcn_mfma_f32_16x16x32_bf16(pah[mt], bh[nt], acc[mt][nt], 0, 0, 0);
    }

    // ---- transform acc in place to final score values + running argmax ----
    #pragma unroll
    for (int mt = 0; mt < 2; ++mt) {
      int pbase = chunk * 256 + w * 32 + mt * 16 + csub;
      float psa[4];
      *(float4*)psa = *(const float4*)(psq + pbase);
      #pragma unroll
      for (int nt = 0; nt < 4; ++nt) {
        f32x4 o;
        {
          #pragma clang fp contract(off)
          #pragma unroll
          for (int r = 0; r < 4; ++r) {
            float t = (xs[nt] + psa[r]) - 2.0f * acc[mt][nt][r];
            o[r] = -t;
            if (o[r] > best[nt]) { best[nt] = o[r]; bidx[nt] = pbase + r; }
          }
        }
        acc[mt][nt] = o;   // acc now holds final scores
      }
    }

    // ---- two staging+store rounds: waves {4h..4h+3} stage cols [h*128,+128) ----
    #pragma unroll
    for (int h = 0; h < 2; ++h) {
      if ((w >> 2) == h) {
        const int colbase = (w & 3) * 32 + csub;
        #pragma unroll
        for (int mt = 0; mt < 2; ++mt)
          #pragma unroll
          for (int nt = 0; nt < 4; ++nt)
            *(f32x4*)&sbuf[nt * 16 + (l & 15)][colbase + mt * 16] = acc[mt][nt];
      }
      barrier_lds();
      const int gbase = chunk * 256 + h * 128;
      #pragma unroll
      for (int ps = 0; ps < 4; ++ps) {
        int idx = ps * 512 + tid;    // 0..2047
        int row = idx >> 5;          // 0..63 (8 rows per pass)
        int f4  = idx & 31;          // 0..31 (128 cols / 4)
        f32x4 v = *(const f32x4*)&sbuf[row][f4 * 4];
        *((f32x4*)(scores + (size_t)(m0 + row) * K_PROT + gbase + f4 * 4)) = v;
      }
      barrier_lds();   // readers done before next round's writers overwrite sbuf
    }
  }

  // ---- argmax reduce: butterfly over quads, then LDS over waves ----
  #pragma unroll
  for (int nt = 0; nt < 4; ++nt) {
    #pragma unroll
    for (int m = 16; m <= 32; m <<= 1) {
      float ov = __shfl_xor(best[nt], m);
      int   oi = __shfl_xor(bidx[nt], m);
      if (ov > best[nt] || (ov == best[nt] && oi < bidx[nt])) {
        best[nt] = ov; bidx[nt] = oi;
      }
    }
  }
  if (l < 16) {
    #pragma unroll
    for (int nt = 0; nt < 4; ++nt) {
      sv[w][nt * 16 + l] = best[nt];
      si[w][nt * 16 + l] = bidx[nt];
    }
  }
  __syncthreads();
  if (tid < 64) {
    float v = sv[0][tid]; int bi = si[0][tid];
    #pragma unroll
    for (int e = 1; e < 8; ++e) {
      float vv = sv[e][tid]; int ii = si[e][tid];
      if (vv > v || (vv == v && ii < bi)) { v = vv; bi = ii; }
    }
    fidx[tid] = bi;
  }
  __syncthreads();

  // ---- gather matched = original fp32 prototypes[argmax] ----
  #pragma unroll
  for (int q0 = 0; q0 < 4; ++q0) {
    int q = q0 * 512 + tid;          // 0..2047
    int pix = q >> 5, f4 = q & 31;
    float4 v = ((const float4*)(p + (size_t)fidx[pix] * D_DIM))[f4];
    *((f32x4*)(matched + (size_t)(m0 + pix) * D_DIM) + f4) = *(f32x4*)&v;
  }
}

// ---------------------------------------------------------------------------
extern "C" void kernel_launch(void* const* d_in, const int* in_sizes, int n_in,
                              void* d_out, int out_size, void* d_ws, size_t ws_size,
                              hipStream_t stream) {
  const float* x = (const float*)d_in[0];   // [B,N,D] fp32
  const float* p = (const float*)d_in[1];   // [K,D]   fp32

  float* matched = (float*)d_out;                            // [B,N,D]
  float* scores  = (float*)d_out + (size_t)M_TOT * D_DIM;    // [B,N,K]

  float* psq = (float*)d_ws;
  short* pf  = (short*)((char*)d_ws + WS_PF_OFF);

  prep_kernel<<<PSQ_BLOCKS + PFRAG_BLOCKS, 256, 0, stream>>>(p, psq, pf);
  proto_mfma<<<M_TOT / 64, 512, 0, stream>>>(x, p, pf, psq, matched, scores);
}